// Round 1
// baseline (1510.140 us; speedup 1.0000x reference)
//
#include <hip/hip_runtime.h>
#include <math.h>

// ToyPredictor: h' = tanh(h @ W_hh^T + xt*v + c);  y = h'.W_out + b_out
// v = W_xh @ W_in, c = W_xh @ b_in + b_h  (precomputed)
// B=4096, T=512 (511 steps), DIM=128.
// Decomposition: 256 blocks x 512 threads; block owns 16 batch rows for all
// 511 steps. h double-buffered in LDS; W_hh row i in registers of the threads
// owning output column i (4 row-groups x 128 cols = 512 threads, each thread
// computes 4 rows x 1 col). seq/pred tiles staged in LDS.

#define DIM   128
#define TFULL 512
#define TS    511
#define ROWS  16
#define NTHR  512
#define NBLK  256   // 4096 / 16

__global__ void precompute_vc(const float* __restrict__ W_in,
                              const float* __restrict__ b_in,
                              const float* __restrict__ W_xh,
                              const float* __restrict__ b_h,
                              float* __restrict__ ws) {
  const int i = threadIdx.x;   // 128 threads
  float v = 0.f, c = 0.f;
  for (int j = 0; j < DIM; ++j) {
    const float wx = W_xh[i * DIM + j];
    v = fmaf(wx, W_in[j], v);
    c = fmaf(wx, b_in[j], c);
  }
  ws[i] = v;
  ws[DIM + i] = c + b_h[i];
  if (i == 0) ws[2 * DIM] = 0.f;   // zero sse accumulator every launch
}

__global__ __launch_bounds__(NTHR, 2)
void helical_fwd(const float* __restrict__ seq,     // [4096,512]
                 const float* __restrict__ W_hh,    // [128,128]
                 const float* __restrict__ W_out,   // [1,128]
                 const float* __restrict__ b_out,   // [1]
                 const float* __restrict__ ws,      // v[128], c[128]
                 float* __restrict__ sse_accum,     // [1]
                 float* __restrict__ preds) {       // [4096,511]
  __shared__ float hbuf[2][ROWS][DIM];
  __shared__ float seq_s[ROWS][TFULL];
  __shared__ float pred_s[ROWS][TFULL];
  __shared__ float yred[2][8][4];     // [buf][wave][row-in-group]
  __shared__ float sse_red[ROWS];

  const int tid  = threadIdx.x;
  const int bid  = blockIdx.x;
  const int row0 = bid * ROWS;

  // Stage the 16x512 seq tile (contiguous in global) — coalesced float4.
  {
    const float4* src = (const float4*)(seq + (size_t)row0 * TFULL);
    float4* dst = (float4*)(&seq_s[0][0]);
    for (int k = tid; k < ROWS * TFULL / 4; k += NTHR) dst[k] = src[k];
  }
  // h0 = 0
  for (int k = tid; k < ROWS * DIM; k += NTHR) (&hbuf[0][0][0])[k] = 0.f;

  const int i    = tid & (DIM - 1);  // output column
  const int rg   = tid >> 7;         // row group 0..3 (rows rg*4 .. rg*4+3)
  const int wv   = tid >> 6;         // wave 0..7
  const int lane = tid & 63;

  // W_hh row i -> 128 registers (j-loop below is fully unrolled; static idx).
  float w[DIM];
#pragma unroll
  for (int j = 0; j < DIM; j += 4) {
    const float4 t4 = *(const float4*)(W_hh + (size_t)i * DIM + j);
    w[j + 0] = t4.x; w[j + 1] = t4.y; w[j + 2] = t4.z; w[j + 3] = t4.w;
  }
  const float v_i    = ws[i];
  const float c_i    = ws[DIM + i];
  const float wout_i = W_out[i];
  const float bout   = b_out[0];

  float sse = 0.f;   // only tid<16 accumulate
  __syncthreads();

  int cur = 0;
  for (int t = 0; t < TS; ++t) {
    float acc0 = 0.f, acc1 = 0.f, acc2 = 0.f, acc3 = 0.f;
    const float* __restrict__ H0 = &hbuf[cur][rg * 4 + 0][0];
    const float* __restrict__ H1 = &hbuf[cur][rg * 4 + 1][0];
    const float* __restrict__ H2 = &hbuf[cur][rg * 4 + 2][0];
    const float* __restrict__ H3 = &hbuf[cur][rg * 4 + 3][0];
#pragma unroll
    for (int j = 0; j < DIM; j += 4) {
      const float4 a  = *(const float4*)(H0 + j);   // wave-uniform: LDS broadcast
      const float4 b  = *(const float4*)(H1 + j);
      const float4 c4 = *(const float4*)(H2 + j);
      const float4 d  = *(const float4*)(H3 + j);
      acc0 = fmaf(a.x,  w[j], fmaf(a.y,  w[j+1], fmaf(a.z,  w[j+2], fmaf(a.w,  w[j+3], acc0))));
      acc1 = fmaf(b.x,  w[j], fmaf(b.y,  w[j+1], fmaf(b.z,  w[j+2], fmaf(b.w,  w[j+3], acc1))));
      acc2 = fmaf(c4.x, w[j], fmaf(c4.y, w[j+1], fmaf(c4.z, w[j+2], fmaf(c4.w, w[j+3], acc2))));
      acc3 = fmaf(d.x,  w[j], fmaf(d.y,  w[j+1], fmaf(d.z,  w[j+2], fmaf(d.w,  w[j+3], acc3))));
    }

    const int nxt = cur ^ 1;
    float py0, py1, py2, py3;
    {
      const float x0 = seq_s[rg * 4 + 0][t];
      const float x1 = seq_s[rg * 4 + 1][t];
      const float x2 = seq_s[rg * 4 + 2][t];
      const float x3 = seq_s[rg * 4 + 3][t];
      const float p0 = fmaf(x0, v_i, acc0) + c_i;
      const float p1 = fmaf(x1, v_i, acc1) + c_i;
      const float p2 = fmaf(x2, v_i, acc2) + c_i;
      const float p3 = fmaf(x3, v_i, acc3) + c_i;
      // tanh(x) = 1 - 2/(e^{2x}+1)
      const float e0 = __expf(2.f * p0);
      const float e1 = __expf(2.f * p1);
      const float e2 = __expf(2.f * p2);
      const float e3 = __expf(2.f * p3);
      const float th0 = 1.f - 2.f / (e0 + 1.f);
      const float th1 = 1.f - 2.f / (e1 + 1.f);
      const float th2 = 1.f - 2.f / (e2 + 1.f);
      const float th3 = 1.f - 2.f / (e3 + 1.f);
      hbuf[nxt][rg * 4 + 0][i] = th0;
      hbuf[nxt][rg * 4 + 1][i] = th1;
      hbuf[nxt][rg * 4 + 2][i] = th2;
      hbuf[nxt][rg * 4 + 3][i] = th3;
      py0 = th0 * wout_i; py1 = th1 * wout_i;
      py2 = th2 * wout_i; py3 = th3 * wout_i;
    }
    // y partials: butterfly over the 64 lanes (each wave covers 64 of 128 cols)
#pragma unroll
    for (int off = 32; off; off >>= 1) {
      py0 += __shfl_xor(py0, off);
      py1 += __shfl_xor(py1, off);
      py2 += __shfl_xor(py2, off);
      py3 += __shfl_xor(py3, off);
    }
    if (lane == 0) {
      yred[t & 1][wv][0] = py0; yred[t & 1][wv][1] = py1;
      yred[t & 1][wv][2] = py2; yred[t & 1][wv][3] = py3;
    }
    __syncthreads();   // hbuf[nxt] + yred visible

    if (tid < ROWS) {   // one thread per batch row: finalize y, pred, loss
      const int r = tid;
      const float y = yred[t & 1][(r >> 2) * 2 + 0][r & 3]
                    + yred[t & 1][(r >> 2) * 2 + 1][r & 3] + bout;
      pred_s[r][t] = y;
      const float d = y - seq_s[r][t + 1];
      sse = fmaf(d, d, sse);
    }
    cur ^= 1;
  }

  if (tid < ROWS) sse_red[tid] = sse;
  __syncthreads();

  // Coalesced pred writeback: out[(row0+r)*511 + t]
  for (int r = 0; r < ROWS; ++r) {
    for (int t2 = tid; t2 < TS; t2 += NTHR)
      preds[(size_t)(row0 + r) * TS + t2] = pred_s[r][t2];
  }
  if (tid == 0) {
    float s = 0.f;
#pragma unroll
    for (int r2 = 0; r2 < ROWS; ++r2) s += sse_red[r2];
    atomicAdd(sse_accum, s);
  }
}

__global__ void finalize_loss(const float* __restrict__ sse,
                              float* __restrict__ out) {
  out[(size_t)4096 * TS] = sse[0] * (1.0f / (4096.0f * (float)TS));
}

extern "C" void kernel_launch(void* const* d_in, const int* in_sizes, int n_in,
                              void* d_out, int out_size, void* d_ws, size_t ws_size,
                              hipStream_t stream) {
  const float* seq   = (const float*)d_in[0];
  const float* W_in  = (const float*)d_in[1];
  const float* b_in  = (const float*)d_in[2];
  const float* W_hh  = (const float*)d_in[3];
  const float* W_xh  = (const float*)d_in[4];
  const float* b_h   = (const float*)d_in[5];
  const float* W_out = (const float*)d_in[6];
  const float* b_out = (const float*)d_in[7];
  float* out = (float*)d_out;
  float* ws  = (float*)d_ws;   // ws[0..127]=v, ws[128..255]=c, ws[256]=sse

  precompute_vc<<<1, DIM, 0, stream>>>(W_in, b_in, W_xh, b_h, ws);
  helical_fwd<<<NBLK, NTHR, 0, stream>>>(seq, W_hh, W_out, b_out, ws,
                                         ws + 2 * DIM, out);
  finalize_loss<<<1, 1, 0, stream>>>(ws + 2 * DIM, out);
}

// Round 2
// 433.738 us; speedup vs baseline: 3.4817x; 3.4817x over previous
//
#include <hip/hip_runtime.h>
#include <math.h>

// ToyPredictor: h' = tanh(h @ W_hh^T + xt*v + c);  y = h'.W_out + b_out
// v = W_xh @ W_in, c = W_xh @ b_in + b_h  (precomputed on device)
// B=4096, T=512 (511 steps), DIM=128.
//
// Round-2 design: per-block 16 batch rows for all 511 steps; the per-step
// 16x128 @ 128x128 matvec runs on MFMA (16x16x32 bf16) with a 2-term
// bf16 hi/lo split (hi*hi + hi*lo + lo*hi) for ~fp32 accuracy.
// 4 waves/block; wave owns 2 col-tiles (W_hh fragments in registers).
// h double-buffered in LDS as bf16 hi/lo planes, XOR-swizzled
// (row-major [16][256B] read at fixed k-offset is a 16-way conflict).
// y-reduction via DPP row_ror rotate-add (VALU pipe, not LDS pipe).

#define DIM   128
#define TFULL 512
#define TS    511
#define ROWS  16
#define NTHR  256
#define NBLK  256   // 4096 / 16

typedef __attribute__((ext_vector_type(8))) short short8;
typedef __attribute__((ext_vector_type(4))) float f32x4;

static __device__ __forceinline__ unsigned short bf16_rne(float x) {
  unsigned u = __float_as_uint(x);
  u += 0x7fffu + ((u >> 16) & 1u);
  return (unsigned short)(u >> 16);
}

__global__ void precompute_vc(const float* __restrict__ W_in,
                              const float* __restrict__ b_in,
                              const float* __restrict__ W_xh,
                              const float* __restrict__ b_h,
                              float* __restrict__ ws) {
  const int i = threadIdx.x;   // 128 threads
  float v = 0.f, c = 0.f;
  for (int j = 0; j < DIM; ++j) {
    const float wx = W_xh[i * DIM + j];
    v = fmaf(wx, W_in[j], v);
    c = fmaf(wx, b_in[j], c);
  }
  ws[i] = v;
  ws[DIM + i] = c + b_h[i];
  if (i == 0) ws[2 * DIM] = 0.f;   // zero sse accumulator every launch
}

__global__ __launch_bounds__(NTHR, 1)
void helical_fwd(const float* __restrict__ seq,     // [4096,512]
                 const float* __restrict__ W_hh,    // [128,128]
                 const float* __restrict__ W_out,   // [1,128]
                 const float* __restrict__ b_out,   // [1]
                 const float* __restrict__ ws,      // v[128], c[128]
                 float* __restrict__ sse_accum,     // [1]
                 float* __restrict__ preds) {       // [4096,511]
  __shared__ unsigned short hHi[2][ROWS][DIM];   // 4 KiB per plane
  __shared__ unsigned short hLo[2][ROWS][DIM];
  __shared__ float seq_s[ROWS][TFULL];
  __shared__ float pred_s[ROWS][TFULL];
  __shared__ float yred[2][4][ROWS];
  __shared__ float sse_red[ROWS];

  const int tid  = threadIdx.x;
  const int wv   = tid >> 6;     // wave 0..3
  const int lane = tid & 63;
  const int l15  = lane & 15;
  const int lk   = lane >> 4;    // 0..3
  const int row0 = blockIdx.x * ROWS;

  // Stage the 16x512 seq tile (contiguous in global) — coalesced float4.
  {
    const float4* src = (const float4*)(seq + (size_t)row0 * TFULL);
    float4* dst = (float4*)(&seq_s[0][0]);
#pragma unroll
    for (int k = 0; k < 8; ++k) dst[tid + k * NTHR] = src[tid + k * NTHR];
  }
  // h0 = 0: zero plane 0 of both hi/lo arrays (4096 B each = 256 x 16 B).
  {
    uint4 z; z.x = z.y = z.z = z.w = 0u;
    ((uint4*)hHi)[tid] = z;
    ((uint4*)hLo)[tid] = z;
  }

  // B fragments: W_hh rows for this wave's 2 col-tiles, split hi/lo bf16.
  // mfma_f32_16x16x32_bf16 B layout: col = lane&15, k = (lane>>4)*8 + e.
  // B[k][col] = W_hh[col][k]  (we need h @ W_hh^T).
  short8 bH[2][4], bL[2][4];
  float v_t[2], c_t[2], wo_t[2];
#pragma unroll
  for (int tt = 0; tt < 2; ++tt) {
    const int colg = (wv * 2 + tt) * 16 + l15;
    v_t[tt]  = ws[colg];
    c_t[tt]  = ws[DIM + colg];
    wo_t[tt] = W_out[colg];
    const float* wr = W_hh + (size_t)colg * DIM + lk * 8;
#pragma unroll
    for (int kk = 0; kk < 4; ++kk) {
      float f[8];
      const float4 p0 = *(const float4*)(wr + kk * 32);
      const float4 p1 = *(const float4*)(wr + kk * 32 + 4);
      f[0] = p0.x; f[1] = p0.y; f[2] = p0.z; f[3] = p0.w;
      f[4] = p1.x; f[5] = p1.y; f[6] = p1.z; f[7] = p1.w;
#pragma unroll
      for (int e = 0; e < 8; ++e) {
        const unsigned short h = bf16_rne(f[e]);
        const float hf = __uint_as_float((unsigned)h << 16);
        const unsigned short l = bf16_rne(f[e] - hf);
        bH[tt][kk][e] = (short)h;
        bL[tt][kk][e] = (short)l;
      }
    }
  }
  const float bout = b_out[0];
  float sse = 0.f;

  // A-frag LDS addressing: row = lane&15, k = (lane>>4)*8 + e (bf16).
  const int abase = l15 * 256 + lk * 16;     // bytes within one plane
  const int aswz  = (l15 & 7) << 4;          // XOR bank swizzle
  char* hHiB = (char*)&hHi[0][0][0];
  char* hLoB = (char*)&hLo[0][0][0];

  __syncthreads();

  for (int t = 0; t < TS; ++t) {
    const int cur = t & 1, nxt = cur ^ 1;

    float xt[4];
#pragma unroll
    for (int r = 0; r < 4; ++r) xt[r] = seq_s[lk * 4 + r][t];

    short8 aH[4], aL[4];
#pragma unroll
    for (int kk = 0; kk < 4; ++kk) {
      const int o = ((abase + kk * 64) ^ aswz) + cur * 4096;
      aH[kk] = *(const short8*)(hHiB + o);
      aL[kk] = *(const short8*)(hLoB + o);
    }

    // acc init: C layout col = lane&15 (+tile), row = (lane>>4)*4 + r.
    f32x4 am[2], a1[2], a2[2];
#pragma unroll
    for (int tt = 0; tt < 2; ++tt) {
#pragma unroll
      for (int r = 0; r < 4; ++r) {
        am[tt][r] = fmaf(xt[r], v_t[tt], c_t[tt]);
        a1[tt][r] = 0.f;
        a2[tt][r] = 0.f;
      }
    }
    // 6 independent chains of 4 MFMAs: hi*hi, hi*lo, lo*hi per tile.
#pragma unroll
    for (int kk = 0; kk < 4; ++kk) {
#pragma unroll
      for (int tt = 0; tt < 2; ++tt) {
        am[tt] = __builtin_amdgcn_mfma_f32_16x16x32_bf16(aH[kk], bH[tt][kk], am[tt], 0, 0, 0);
        a1[tt] = __builtin_amdgcn_mfma_f32_16x16x32_bf16(aH[kk], bL[tt][kk], a1[tt], 0, 0, 0);
        a2[tt] = __builtin_amdgcn_mfma_f32_16x16x32_bf16(aL[kk], bH[tt][kk], a2[tt], 0, 0, 0);
      }
    }

    float py[4] = {0.f, 0.f, 0.f, 0.f};
#pragma unroll
    for (int tt = 0; tt < 2; ++tt) {
      const f32x4 pre = am[tt] + a1[tt] + a2[tt];
      const int colg = (wv * 2 + tt) * 16 + l15;
#pragma unroll
      for (int r = 0; r < 4; ++r) {
        const float p = pre[r];
        // tanh(p) = 1 - 2/(e^{2p}+1); rcp + 1 Newton step (~2^-28)
        const float e   = __expf(2.f * p);
        const float den = e + 1.f;
        float rc = __builtin_amdgcn_rcpf(den);
        rc = rc * (2.f - den * rc);
        const float th = fmaf(-2.f, rc, 1.f);
        const unsigned short hi = bf16_rne(th);
        const float hf = __uint_as_float((unsigned)hi << 16);
        const unsigned short lo = bf16_rne(th - hf);
        const int rowW = lk * 4 + r;
        const int wo = ((rowW * 256 + colg * 2) ^ ((rowW & 7) << 4)) + nxt * 4096;
        *(unsigned short*)(hHiB + wo) = hi;
        *(unsigned short*)(hLoB + wo) = lo;
        py[r] = fmaf(th, wo_t[tt], py[r]);
      }
    }

    // y partial: sum over this wave's 16 cols via DPP row_ror rotate-add
    // (16-lane rows; shifts 8,4,2,1 give every lane the full row sum).
#pragma unroll
    for (int r = 0; r < 4; ++r) {
      float x = py[r];
      x += __int_as_float(__builtin_amdgcn_update_dpp(0, __float_as_int(x), 0x128, 0xf, 0xf, true));
      x += __int_as_float(__builtin_amdgcn_update_dpp(0, __float_as_int(x), 0x124, 0xf, 0xf, true));
      x += __int_as_float(__builtin_amdgcn_update_dpp(0, __float_as_int(x), 0x122, 0xf, 0xf, true));
      x += __int_as_float(__builtin_amdgcn_update_dpp(0, __float_as_int(x), 0x121, 0xf, 0xf, true));
      py[r] = x;
    }
    if (l15 == 0) {
#pragma unroll
      for (int r = 0; r < 4; ++r) yred[t & 1][wv][lk * 4 + r] = py[r];
    }

    __syncthreads();   // h'[nxt] + yred visible

    if (tid < ROWS) {   // finalize y, pred, loss for this step
      const float y = yred[t & 1][0][tid] + yred[t & 1][1][tid]
                    + yred[t & 1][2][tid] + yred[t & 1][3][tid] + bout;
      pred_s[tid][t] = y;
      const float d = y - seq_s[tid][t + 1];
      sse = fmaf(d, d, sse);
    }
  }

  if (tid < ROWS) sse_red[tid] = sse;
  __syncthreads();

  // Coalesced pred writeback: out[(row0+r)*511 + t]
#pragma unroll
  for (int r = 0; r < ROWS; ++r) {
    for (int t2 = tid; t2 < TS; t2 += NTHR)
      preds[(size_t)(row0 + r) * TS + t2] = pred_s[r][t2];
  }
  if (tid == 0) {
    float s = 0.f;
#pragma unroll
    for (int r2 = 0; r2 < ROWS; ++r2) s += sse_red[r2];
    atomicAdd(sse_accum, s);
  }
}

__global__ void finalize_loss(const float* __restrict__ sse,
                              float* __restrict__ out) {
  out[(size_t)4096 * TS] = sse[0] * (1.0f / (4096.0f * (float)TS));
}

extern "C" void kernel_launch(void* const* d_in, const int* in_sizes, int n_in,
                              void* d_out, int out_size, void* d_ws, size_t ws_size,
                              hipStream_t stream) {
  const float* seq   = (const float*)d_in[0];
  const float* W_in  = (const float*)d_in[1];
  const float* b_in  = (const float*)d_in[2];
  const float* W_hh  = (const float*)d_in[3];
  const float* W_xh  = (const float*)d_in[4];
  const float* b_h   = (const float*)d_in[5];
  const float* W_out = (const float*)d_in[6];
  const float* b_out = (const float*)d_in[7];
  float* out = (float*)d_out;
  float* ws  = (float*)d_ws;   // ws[0..127]=v, ws[128..255]=c, ws[256]=sse

  precompute_vc<<<1, DIM, 0, stream>>>(W_in, b_in, W_xh, b_h, ws);
  helical_fwd<<<NBLK, NTHR, 0, stream>>>(seq, W_hh, W_out, b_out, ws,
                                         ws + 2 * DIM, out);
  finalize_loss<<<1, 1, 0, stream>>>(ws + 2 * DIM, out);
}

// Round 3
// 403.736 us; speedup vs baseline: 3.7404x; 1.0743x over previous
//
#include <hip/hip_runtime.h>
#include <math.h>

// ToyPredictor: h' = tanh(h @ W_hh^T + xt*v + c);  y = h'.W_out + b_out
// v = W_xh @ W_in, c = W_xh @ b_in + b_h  (precomputed on device)
// B=4096, T=512 (511 steps), DIM=128.
//
// Round-3: fragment-linear LDS layout for h (reads are linear ds_read_b128,
// zero extra bank conflicts); y computed on the MFMA pipe (W_out as B-frag
// col 0) one step deferred; truncation hi + rne lo split (5 ops); preds
// stored direct to global; manual lgkmcnt(0)+s_barrier (no vmcnt drain);
// t-loop unrolled x2 so all LDS buffer offsets are immediates.

#define DIM   128
#define TFULL 512
#define TS    511
#define ROWS  16
#define NTHR  256
#define NBLK  256   // 4096 / 16
#define SEQP  20    // padded row stride (floats) for transposed seq tile

typedef __attribute__((ext_vector_type(8))) short short8;
typedef __attribute__((ext_vector_type(4))) float f32x4;

static __device__ __forceinline__ unsigned short bf16_rne(float x) {
  unsigned u = __float_as_uint(x);
  u += 0x7fffu + ((u >> 16) & 1u);
  return (unsigned short)(u >> 16);
}

__global__ void precompute_vc(const float* __restrict__ W_in,
                              const float* __restrict__ b_in,
                              const float* __restrict__ W_xh,
                              const float* __restrict__ b_h,
                              float* __restrict__ ws) {
  const int i = threadIdx.x;   // 128 threads
  float v = 0.f, c = 0.f;
  for (int j = 0; j < DIM; ++j) {
    const float wx = W_xh[i * DIM + j];
    v = fmaf(wx, W_in[j], v);
    c = fmaf(wx, b_in[j], c);
  }
  ws[i] = v;
  ws[DIM + i] = c + b_h[i];
  if (i == 0) ws[2 * DIM] = 0.f;   // zero sse accumulator every launch
}

__global__ __launch_bounds__(NTHR, 1)
void helical_fwd(const float* __restrict__ seq,     // [4096,512]
                 const float* __restrict__ W_hh,    // [128,128]
                 const float* __restrict__ W_out,   // [1,128]
                 const float* __restrict__ b_out,   // [1]
                 const float* __restrict__ ws,      // v[128], c[128]
                 float* __restrict__ sse_accum,     // [1]
                 float* __restrict__ preds) {       // [4096,511]
  // h planes, fragment-linear: element (row,k) of h lives at
  //   byte = (k>>5)*1024 + phys*16 + (k&7)*2,  ln = row + 16*((k>>3)&3),
  //   phys = ln ^ (ln>>3)   (spreads 16B slots across all 32 banks)
  // buf b at +b*8192; lo plane at +4096.
  __shared__ __align__(16) unsigned short hpl[2][2][2048];   // 16 KiB
  __shared__ __align__(16) float seqT[TFULL * SEQP];         // 40 KiB

  const int tid  = threadIdx.x;
  const int wv   = tid >> 6;     // wave 0..3
  const int lane = tid & 63;
  const int l15  = lane & 15;
  const int lk   = lane >> 4;    // 0..3
  const int row0 = blockIdx.x * ROWS;
  char* hb = (char*)hpl;

  // Stage seq transposed: seqT[t*SEQP + row] = seq[row0+row][t]
  {
    const float4* src = (const float4*)(seq + (size_t)row0 * TFULL);
#pragma unroll
    for (int k0 = 0; k0 < 8; ++k0) {
      const int k = tid + k0 * NTHR;         // 2048 float4 total
      const float4 v = src[k];
      const int r  = k >> 7;                 // 128 float4 per row
      const int t0 = (k & 127) << 2;
      seqT[(t0 + 0) * SEQP + r] = v.x;
      seqT[(t0 + 1) * SEQP + r] = v.y;
      seqT[(t0 + 2) * SEQP + r] = v.z;
      seqT[(t0 + 3) * SEQP + r] = v.w;
    }
  }
  // h0 = 0: zero buf0 hi+lo (8192 B)
  {
    uint4 z; z.x = z.y = z.z = z.w = 0u;
    ((uint4*)hb)[tid] = z;
    ((uint4*)hb)[tid + NTHR] = z;
  }

  // B fragments (W_hh^T), hi/lo bf16 split. B layout: col = lane&15,
  // k = (lane>>4)*8 + e;  B[k][col] = W_hh[col][k].
  short8 bH[2][4], bL[2][4], bWH[4];
  float v_t[2], c_t[2];
#pragma unroll
  for (int tt = 0; tt < 2; ++tt) {
    const int colg = (wv * 2 + tt) * 16 + l15;
    v_t[tt] = ws[colg];
    c_t[tt] = ws[DIM + colg];
    const float* wr = W_hh + (size_t)colg * DIM + lk * 8;
#pragma unroll
    for (int kk = 0; kk < 4; ++kk) {
      float f[8];
      const float4 p0 = *(const float4*)(wr + kk * 32);
      const float4 p1 = *(const float4*)(wr + kk * 32 + 4);
      f[0] = p0.x; f[1] = p0.y; f[2] = p0.z; f[3] = p0.w;
      f[4] = p1.x; f[5] = p1.y; f[6] = p1.z; f[7] = p1.w;
#pragma unroll
      for (int e = 0; e < 8; ++e) {
        const unsigned short h = bf16_rne(f[e]);
        const float hf = __uint_as_float((unsigned)h << 16);
        bH[tt][kk][e] = (short)h;
        bL[tt][kk][e] = (short)bf16_rne(f[e] - hf);
      }
    }
  }
  // W_out as B-frag with only col 0 populated (for y via MFMA).
#pragma unroll
  for (int kk = 0; kk < 4; ++kk) {
#pragma unroll
    for (int e = 0; e < 8; ++e) {
      const int kg = kk * 32 + lk * 8 + e;
      const float f = (l15 == 0) ? W_out[kg] : 0.f;
      bWH[kk][e] = (short)bf16_rne(f);
    }
  }
  const float bout = b_out[0];

  // A-frag read base: linear 16B per lane, XOR-spread.
  const int rdb = ((lane ^ (lane >> 3)) << 4);

  // Writer byte offsets (hi plane; lo at +4096), per [nxt-buf][tile][r].
  int wa[2][2][4];
#pragma unroll
  for (int tt = 0; tt < 2; ++tt) {
    const int colg = (wv * 2 + tt) * 16 + l15;
    const int kkw = colg >> 5, ksw = (colg >> 3) & 3, ew = colg & 7;
#pragma unroll
    for (int r = 0; r < 4; ++r) {
      const int ln  = lk * 4 + r + (ksw << 4);
      const int ph  = ln ^ (ln >> 3);
      const int off = (kkw << 10) + (ph << 4) + (ew << 1);
      wa[0][tt][r] = off;
      wa[1][tt][r] = off + 8192;
    }
  }

  float sse = 0.f;
  int idx[4];
#pragma unroll
  for (int r = 0; r < 4; ++r) idx[r] = (row0 + lk * 4 + r) * TS;
  int xoff = lk * 4;

  __syncthreads();

#define STEP(CUR, DO_Y)                                                        \
  {                                                                            \
    const f32x4 xv = *(const f32x4*)(&seqT[xoff]);                             \
    short8 aH[4], aL[4];                                                       \
    _Pragma("unroll")                                                          \
    for (int kk = 0; kk < 4; ++kk) {                                           \
      aH[kk] = *(const short8*)(hb + (CUR)*8192 + kk*1024 + rdb);              \
      aL[kk] = *(const short8*)(hb + (CUR)*8192 + 4096 + kk*1024 + rdb);       \
    }                                                                          \
    f32x4 accP[2], accQ[2];                                                    \
    _Pragma("unroll")                                                          \
    for (int tt = 0; tt < 2; ++tt) {                                           \
      accP[tt][0] = fmaf(xv[0], v_t[tt], c_t[tt]);                             \
      accP[tt][1] = fmaf(xv[1], v_t[tt], c_t[tt]);                             \
      accP[tt][2] = fmaf(xv[2], v_t[tt], c_t[tt]);                             \
      accP[tt][3] = fmaf(xv[3], v_t[tt], c_t[tt]);                             \
      accQ[tt] = (f32x4){0.f, 0.f, 0.f, 0.f};                                  \
    }                                                                          \
    _Pragma("unroll")                                                          \
    for (int kk = 0; kk < 4; ++kk) {                                           \
      _Pragma("unroll")                                                        \
      for (int tt = 0; tt < 2; ++tt) {                                         \
        accP[tt] = __builtin_amdgcn_mfma_f32_16x16x32_bf16(aH[kk], bH[tt][kk], accP[tt], 0, 0, 0); \
        accQ[tt] = __builtin_amdgcn_mfma_f32_16x16x32_bf16(aH[kk], bL[tt][kk], accQ[tt], 0, 0, 0); \
        accQ[tt] = __builtin_amdgcn_mfma_f32_16x16x32_bf16(aL[kk], bH[tt][kk], accQ[tt], 0, 0, 0); \
      }                                                                        \
    }                                                                          \
    if ((DO_Y) && wv == 0) {                                                   \
      f32x4 y1 = {0.f,0.f,0.f,0.f}, y2 = {0.f,0.f,0.f,0.f};                    \
      _Pragma("unroll")                                                        \
      for (int kk = 0; kk < 4; ++kk) {                                         \
        y1 = __builtin_amdgcn_mfma_f32_16x16x32_bf16(aH[kk], bWH[kk], y1, 0, 0, 0); \
        y2 = __builtin_amdgcn_mfma_f32_16x16x32_bf16(aL[kk], bWH[kk], y2, 0, 0, 0); \
      }                                                                        \
      if (l15 == 0) {                                                          \
        _Pragma("unroll")                                                      \
        for (int r = 0; r < 4; ++r) {                                          \
          const float y = y1[r] + y2[r] + bout;                                \
          const float d = y - xv[r];                                           \
          sse = fmaf(d, d, sse);                                               \
          preds[idx[r]] = y;                                                   \
          idx[r] += 1;                                                         \
        }                                                                      \
      }                                                                        \
    }                                                                          \
    _Pragma("unroll")                                                          \
    for (int tt = 0; tt < 2; ++tt) {                                           \
      const f32x4 pre = accP[tt] + accQ[tt];                                   \
      _Pragma("unroll")                                                        \
      for (int r = 0; r < 4; ++r) {                                            \
        const float p  = pre[r];                                               \
        const float ex = __expf(2.f * p);                                      \
        const float rc = __builtin_amdgcn_rcpf(ex + 1.f);                      \
        const float th = fmaf(-2.f, rc, 1.f);                                  \
        const unsigned u = __float_as_uint(th);                                \
        *(unsigned short*)(hb + wa[(CUR)^1][tt][r]) = (unsigned short)(u >> 16); \
        const float hf = __uint_as_float(u & 0xffff0000u);                     \
        const float rl = th - hf;                                              \
        unsigned ul = __float_as_uint(rl);                                     \
        ul += 0x7fffu + ((ul >> 16) & 1u);                                     \
        *(unsigned short*)(hb + 4096 + wa[(CUR)^1][tt][r]) = (unsigned short)(ul >> 16); \
      }                                                                        \
    }                                                                          \
    xoff += SEQP;                                                              \
    __builtin_amdgcn_sched_barrier(0);                                         \
    asm volatile("s_waitcnt lgkmcnt(0)" ::: "memory");                         \
    __builtin_amdgcn_s_barrier();                                              \
    __builtin_amdgcn_sched_barrier(0);                                         \
  }

  STEP(0, false)                    // t = 0 (y_{-1} skipped)
  for (int tq = 0; tq < 255; ++tq) {
    STEP(1, true)                   // odd t
    STEP(0, true)                   // even t
  }
  // 511 steps done; h_511 is in buf1. Tail: y_510 + final loss terms.
  if (wv == 0) {
    short8 tH[4], tL[4];
#pragma unroll
    for (int kk = 0; kk < 4; ++kk) {
      tH[kk] = *(const short8*)(hb + 8192 + kk * 1024 + rdb);
      tL[kk] = *(const short8*)(hb + 8192 + 4096 + kk * 1024 + rdb);
    }
    f32x4 y1 = {0.f,0.f,0.f,0.f}, y2 = {0.f,0.f,0.f,0.f};
#pragma unroll
    for (int kk = 0; kk < 4; ++kk) {
      y1 = __builtin_amdgcn_mfma_f32_16x16x32_bf16(tH[kk], bWH[kk], y1, 0, 0, 0);
      y2 = __builtin_amdgcn_mfma_f32_16x16x32_bf16(tL[kk], bWH[kk], y2, 0, 0, 0);
    }
    const f32x4 xv = *(const f32x4*)(&seqT[xoff]);   // seq[:,511] targets
    if (l15 == 0) {
#pragma unroll
      for (int r = 0; r < 4; ++r) {
        const float y = y1[r] + y2[r] + bout;
        const float d = y - xv[r];
        sse = fmaf(d, d, sse);
        preds[idx[r]] = y;
      }
    }
    float s = (l15 == 0) ? sse : 0.f;
    s += __shfl_xor(s, 16);
    s += __shfl_xor(s, 32);
    if (lane == 0) atomicAdd(sse_accum, s);
  }
#undef STEP
}

__global__ void finalize_loss(const float* __restrict__ sse,
                              float* __restrict__ out) {
  out[(size_t)4096 * TS] = sse[0] * (1.0f / (4096.0f * (float)TS));
}

extern "C" void kernel_launch(void* const* d_in, const int* in_sizes, int n_in,
                              void* d_out, int out_size, void* d_ws, size_t ws_size,
                              hipStream_t stream) {
  const float* seq   = (const float*)d_in[0];
  const float* W_in  = (const float*)d_in[1];
  const float* b_in  = (const float*)d_in[2];
  const float* W_hh  = (const float*)d_in[3];
  const float* W_xh  = (const float*)d_in[4];
  const float* b_h   = (const float*)d_in[5];
  const float* W_out = (const float*)d_in[6];
  const float* b_out = (const float*)d_in[7];
  float* out = (float*)d_out;
  float* ws  = (float*)d_ws;   // ws[0..127]=v, ws[128..255]=c, ws[256]=sse

  precompute_vc<<<1, DIM, 0, stream>>>(W_in, b_in, W_xh, b_h, ws);
  helical_fwd<<<NBLK, NTHR, 0, stream>>>(seq, W_hh, W_out, b_out, ws,
                                         ws + 2 * DIM, out);
  finalize_loss<<<1, 1, 0, stream>>>(ws + 2 * DIM, out);
}

// Round 4
// 337.807 us; speedup vs baseline: 4.4704x; 1.1952x over previous
//
#include <hip/hip_runtime.h>
#include <math.h>

// ToyPredictor: h' = tanh(h @ W_hh^T + xt*v + c);  y = h'.W_out + b_out
// v = W_xh @ W_in, c = W_xh @ b_in + b_h  (precomputed on device)
// B=4096, T=512 (511 steps), DIM=128.
//
// Round-4: TRANSPOSED recurrence S' = tanh(W_hh @ S + v xt^T + c), S = h^T
// [dim][batch]. A-frags = W_hh rows (static, registers). C layout
// (col=lane&15=batch) matches B layout (col=lane&15=batch): a lane's 4 acc
// regs are 4 consecutive dims of one batch -> h' writes are 4x ds_write_b64
// (bf16 pairs packed with v_perm) instead of 16x b16. S planes XOR-swizzled
// ((l15&7)<<4, bijective, verified writer==reader byte mapping); B-frag
// ds_read_b128 is then linear-equivalent (conflict-free). y via in-register
// fma + shfl_xor(16,32); prev-step finalize at top of step (overlaps loads);
// persistent-zero C operand for correction chains; compiler-only fences
// around the manual lgkmcnt(0)+s_barrier.

#define DIM    128
#define TFULL  512
#define TS     511
#define NTHR   256
#define NBLK   256   // 4096 / 16 rows per block
#define SEQPAD 18

typedef __attribute__((ext_vector_type(8))) short short8;
typedef __attribute__((ext_vector_type(4))) float f32x4;

static __device__ __forceinline__ unsigned short bf16_rne(float x) {
  unsigned u = __float_as_uint(x);
  u += 0x7fffu + ((u >> 16) & 1u);
  return (unsigned short)(u >> 16);
}

__global__ void precompute_vc(const float* __restrict__ W_in,
                              const float* __restrict__ b_in,
                              const float* __restrict__ W_xh,
                              const float* __restrict__ b_h,
                              float* __restrict__ ws) {
  const int i = threadIdx.x;   // 128 threads
  float v = 0.f, c = 0.f;
  for (int j = 0; j < DIM; ++j) {
    const float wx = W_xh[i * DIM + j];
    v = fmaf(wx, W_in[j], v);
    c = fmaf(wx, b_in[j], c);
  }
  ws[i] = v;
  ws[DIM + i] = c + b_h[i];
  if (i == 0) ws[2 * DIM] = 0.f;   // zero sse accumulator every launch
}

__global__ __launch_bounds__(NTHR, 1)
void helical_fwd(const float* __restrict__ seq,     // [4096,512]
                 const float* __restrict__ W_hh,    // [128,128]
                 const float* __restrict__ W_out,   // [1,128]
                 const float* __restrict__ b_out,   // [1]
                 const float* __restrict__ ws,      // v[128], c[128]
                 float* __restrict__ sse_accum,     // [1]
                 float* __restrict__ preds) {       // [4096,511]
  // S planes: [buf][plane(hi/lo)][16 batch][128 dim] bf16, 4 KiB per plane.
  // byte(b,d) = b*256 + ((2d & ~7) ^ ((b&7)<<4)) + (2d & 7)
  __shared__ __align__(16) unsigned short Spl[2][2][2048];   // 16 KiB
  __shared__ __align__(16) float seqT[TFULL * SEQPAD];       // 36 KiB
  __shared__ float yred[2][4][16];

  const int tid  = threadIdx.x;
  const int wv   = tid >> 6;     // wave 0..3 (owns dims 32*wv .. 32*wv+31)
  const int lane = tid & 63;
  const int l15  = lane & 15;    // batch col (C/B layout) / W row (A layout)
  const int lk   = lane >> 4;    // 0..3
  const int row0 = blockIdx.x * 16;
  char* hbB = (char*)Spl;

  // Stage seq transposed: seqT[t*SEQPAD + b] = seq[row0+b][t]
  {
    const float4* src = (const float4*)(seq + (size_t)row0 * TFULL);
#pragma unroll
    for (int k0 = 0; k0 < 8; ++k0) {
      const int k = tid + k0 * NTHR;         // 2048 float4 total
      const float4 v = src[k];
      const int r  = k >> 7;
      const int t0 = (k & 127) << 2;
      seqT[(t0 + 0) * SEQPAD + r] = v.x;
      seqT[(t0 + 1) * SEQPAD + r] = v.y;
      seqT[(t0 + 2) * SEQPAD + r] = v.z;
      seqT[(t0 + 3) * SEQPAD + r] = v.w;
    }
  }
  // S0 = 0: zero buf0 hi+lo (8192 B)
  {
    uint4 z; z.x = z.y = z.z = z.w = 0u;
    ((uint4*)hbB)[tid] = z;
    ((uint4*)hbB)[tid + NTHR] = z;
  }

  // A-frags: W_hh, hi/lo bf16 split. A layout: row = lane&15 (out-dim in
  // tile), k = (lane>>4)*8 + e.  wH[tt][kk][e] = W[32wv+16tt+l15][32kk+8lk+e]
  short8 wH[2][4], wL[2][4];
  float vr[2][4], cr[2][4], wo[2][4];
#pragma unroll
  for (int tt = 0; tt < 2; ++tt) {
    const int rowW = 32 * wv + 16 * tt + l15;
    const float* wr = W_hh + (size_t)rowW * DIM + 8 * lk;
#pragma unroll
    for (int kk = 0; kk < 4; ++kk) {
      float f[8];
      const float4 p0 = *(const float4*)(wr + 32 * kk);
      const float4 p1 = *(const float4*)(wr + 32 * kk + 4);
      f[0] = p0.x; f[1] = p0.y; f[2] = p0.z; f[3] = p0.w;
      f[4] = p1.x; f[5] = p1.y; f[6] = p1.z; f[7] = p1.w;
#pragma unroll
      for (int e = 0; e < 8; ++e) {
        const unsigned short h = bf16_rne(f[e]);
        const float hf = __uint_as_float((unsigned)h << 16);
        wH[tt][kk][e] = (short)h;
        wL[tt][kk][e] = (short)bf16_rne(f[e] - hf);
      }
    }
    const int dbase = 32 * wv + 16 * tt + 4 * lk;   // this lane's 4 dims
#pragma unroll
    for (int r = 0; r < 4; ++r) {
      vr[tt][r] = ws[dbase + r];
      cr[tt][r] = ws[DIM + dbase + r];
      wo[tt][r] = W_out[dbase + r];
    }
  }
  const float bout = b_out[0];

  // LDS addressing (swizzled). Reads: 16B at b*256 + (((kk<<6)|(lk<<4))^swz).
  const int swz = (l15 & 7) << 4;
  const int rdA = l15 * 256 + ((lk << 4) ^ swz);          // kk=0 (kk=2: +128)
  const int rdB = l15 * 256 + ((64 | (lk << 4)) ^ swz);   // kk=1 (kk=3: +128)
  // Writes: 8B at b*256 + (((wv<<6)|(tt<<5)|(lk<<3))^swz), planes +4096.
  const int wA0 = l15 * 256 + (((wv << 6) | (lk << 3)) ^ swz);
  const int wA1 = l15 * 256 + (((wv << 6) | 32 | (lk << 3)) ^ swz);

  const f32x4 ZERO = {0.f, 0.f, 0.f, 0.f};
  float sse = 0.f;
  int xadr = l15;
  int pidx = (row0 + lane) * TS;   // used by wv0 lanes<16

  __syncthreads();

#define STEP(CUR, DOFIN)                                                       \
  {                                                                            \
    const float xtb = seqT[xadr];                                              \
    xadr += SEQPAD;                                                            \
    if ((DOFIN) && wv == 0 && lane < 16) {  /* finalize y_{t-1} */             \
      const float y = yred[(CUR) ^ 1][0][lane] + yred[(CUR) ^ 1][1][lane]      \
                    + yred[(CUR) ^ 1][2][lane] + yred[(CUR) ^ 1][3][lane]      \
                    + bout;                                                    \
      preds[pidx] = y;                                                         \
      pidx += 1;                                                               \
      const float d = y - xtb;                                                 \
      sse = fmaf(d, d, sse);                                                   \
    }                                                                          \
    short8 sH[4], sL[4];                                                       \
    sH[0] = *(const short8*)(hbB + (CUR)*8192 + rdA);                          \
    sH[1] = *(const short8*)(hbB + (CUR)*8192 + rdB);                          \
    sH[2] = *(const short8*)(hbB + (CUR)*8192 + rdA + 128);                    \
    sH[3] = *(const short8*)(hbB + (CUR)*8192 + rdB + 128);                    \
    sL[0] = *(const short8*)(hbB + (CUR)*8192 + 4096 + rdA);                   \
    sL[1] = *(const short8*)(hbB + (CUR)*8192 + 4096 + rdB);                   \
    sL[2] = *(const short8*)(hbB + (CUR)*8192 + 4096 + rdA + 128);             \
    sL[3] = *(const short8*)(hbB + (CUR)*8192 + 4096 + rdB + 128);             \
    f32x4 p[2], q1[2], q2[2];                                                  \
    _Pragma("unroll")                                                          \
    for (int tt = 0; tt < 2; ++tt) {                                           \
      p[tt][0] = fmaf(xtb, vr[tt][0], cr[tt][0]);                              \
      p[tt][1] = fmaf(xtb, vr[tt][1], cr[tt][1]);                              \
      p[tt][2] = fmaf(xtb, vr[tt][2], cr[tt][2]);                              \
      p[tt][3] = fmaf(xtb, vr[tt][3], cr[tt][3]);                              \
    }                                                                          \
    _Pragma("unroll")                                                          \
    for (int tt = 0; tt < 2; ++tt) {                                           \
      _Pragma("unroll")                                                        \
      for (int kk = 0; kk < 4; ++kk) {                                         \
        p[tt]  = __builtin_amdgcn_mfma_f32_16x16x32_bf16(wH[tt][kk], sH[kk], p[tt], 0, 0, 0); \
        q1[tt] = __builtin_amdgcn_mfma_f32_16x16x32_bf16(wH[tt][kk], sL[kk],  \
                     kk ? q1[tt] : ZERO, 0, 0, 0);                             \
        q2[tt] = __builtin_amdgcn_mfma_f32_16x16x32_bf16(wL[tt][kk], sH[kk],  \
                     kk ? q2[tt] : ZERO, 0, 0, 0);                             \
      }                                                                        \
    }                                                                          \
    float py = 0.f;                                                            \
    _Pragma("unroll")                                                          \
    for (int tt = 0; tt < 2; ++tt) {                                           \
      const f32x4 pre = p[tt] + q1[tt] + q2[tt];                               \
      unsigned uh[4], ul[4];                                                   \
      _Pragma("unroll")                                                        \
      for (int r = 0; r < 4; ++r) {                                            \
        const float pv = pre[r];                                               \
        const float ex = __expf(2.f * pv);                                     \
        const float rc = __builtin_amdgcn_rcpf(ex + 1.f);                      \
        const float th = fmaf(-2.f, rc, 1.f);                                  \
        py = fmaf(th, wo[tt][r], py);                                          \
        uh[r] = __float_as_uint(th);                                           \
        const float hf = __uint_as_float(uh[r] & 0xffff0000u);                 \
        const float rl = th - hf;                                              \
        unsigned u2 = __float_as_uint(rl);                                     \
        ul[r] = u2 + 0x7fffu + ((u2 >> 16) & 1u);                              \
      }                                                                        \
      const unsigned h01 = __builtin_amdgcn_perm(uh[1], uh[0], 0x07060302u);   \
      const unsigned h23 = __builtin_amdgcn_perm(uh[3], uh[2], 0x07060302u);   \
      const unsigned l01 = __builtin_amdgcn_perm(ul[1], ul[0], 0x07060302u);   \
      const unsigned l23 = __builtin_amdgcn_perm(ul[3], ul[2], 0x07060302u);   \
      const int wa = tt ? wA1 : wA0;                                           \
      uint2 hv; hv.x = h01; hv.y = h23;                                        \
      uint2 lv; lv.x = l01; lv.y = l23;                                        \
      *(uint2*)(hbB + ((CUR) ^ 1) * 8192 + wa) = hv;                           \
      *(uint2*)(hbB + ((CUR) ^ 1) * 8192 + 4096 + wa) = lv;                    \
    }                                                                          \
    py += __shfl_xor(py, 16);                                                  \
    py += __shfl_xor(py, 32);                                                  \
    if (lane < 16) yred[(CUR)][wv][lane] = py;                                 \
    asm volatile("s_waitcnt lgkmcnt(0)" ::: "memory");                         \
    __builtin_amdgcn_s_barrier();                                              \
    asm volatile("" ::: "memory");                                             \
  }

  STEP(0, false)                    // t = 0
  for (int tq = 0; tq < 255; ++tq) {
    STEP(1, true)                   // odd t
    STEP(0, true)                   // even t
  }
#undef STEP

  // Tail: finalize y_510 (yred[510&1 = 0]); target seq[b][511] at xadr.
  if (wv == 0) {
    if (lane < 16) {
      const float xf = seqT[xadr];
      const float y = yred[0][0][lane] + yred[0][1][lane]
                    + yred[0][2][lane] + yred[0][3][lane] + bout;
      preds[pidx] = y;
      const float d = y - xf;
      sse = fmaf(d, d, sse);
    }
    float s = (lane < 16) ? sse : 0.f;
    s += __shfl_xor(s, 1);
    s += __shfl_xor(s, 2);
    s += __shfl_xor(s, 4);
    s += __shfl_xor(s, 8);
    if (lane == 0) atomicAdd(sse_accum, s);
  }
}

__global__ void finalize_loss(const float* __restrict__ sse,
                              float* __restrict__ out) {
  out[(size_t)4096 * TS] = sse[0] * (1.0f / (4096.0f * (float)TS));
}

extern "C" void kernel_launch(void* const* d_in, const int* in_sizes, int n_in,
                              void* d_out, int out_size, void* d_ws, size_t ws_size,
                              hipStream_t stream) {
  const float* seq   = (const float*)d_in[0];
  const float* W_in  = (const float*)d_in[1];
  const float* b_in  = (const float*)d_in[2];
  const float* W_hh  = (const float*)d_in[3];
  const float* W_xh  = (const float*)d_in[4];
  const float* b_h   = (const float*)d_in[5];
  const float* W_out = (const float*)d_in[6];
  const float* b_out = (const float*)d_in[7];
  float* out = (float*)d_out;
  float* ws  = (float*)d_ws;   // ws[0..127]=v, ws[128..255]=c, ws[256]=sse

  precompute_vc<<<1, DIM, 0, stream>>>(W_in, b_in, W_xh, b_h, ws);
  helical_fwd<<<NBLK, NTHR, 0, stream>>>(seq, W_hh, W_out, b_out, ws,
                                         ws + 2 * DIM, out);
  finalize_loss<<<1, 1, 0, stream>>>(ws + 2 * DIM, out);
}